// Round 6
// baseline (312.253 us; speedup 1.0000x reference)
//
#include <hip/hip_runtime.h>
#include <stdint.h>

#define T_TOK 2048
#define DD 1024
#define EE 8
#define FF 2048
#define NSLOT 4096     // T*K
#define SLOTPAD 4224   // NSLOT + 128 pad rows

typedef __attribute__((ext_vector_type(8))) __bf16 bf16x8;
typedef __attribute__((ext_vector_type(4))) float floatx4;
typedef __attribute__((ext_vector_type(8))) float floatx8;
typedef __attribute__((ext_vector_type(8))) unsigned short ushort8;

__device__ __forceinline__ unsigned short f2bf(float f){
  union { float f; unsigned u; } v; v.f = f;
  unsigned r = v.u + 0x7fffu + ((v.u >> 16) & 1u);
  return (unsigned short)(r >> 16);
}
__device__ __forceinline__ float bf2f(unsigned short h){
  union { unsigned u; float f; } v; v.u = (unsigned)h << 16; return v.f;
}

#define GLDS(src, dst) __builtin_amdgcn_global_load_lds( \
    (__attribute__((address_space(1))) unsigned int*)(src), \
    (__attribute__((address_space(3))) unsigned int*)(dst), 16, 0, 0)

// ---------------- RMSNorm + router (one block per token, NO global atomics) ----
__global__ __launch_bounds__(256) void k_rms_router(
    const float* __restrict__ x, const float* __restrict__ gw,
    const float* __restrict__ nw,
    unsigned short* __restrict__ xn,
    int* __restrict__ topk_id, float* __restrict__ topk_w,
    float* __restrict__ probbuf)
{
  const int t = blockIdx.x, tid = threadIdx.x;
  const float4 xv = ((const float4*)(x + (size_t)t * DD))[tid];
  float ss = xv.x*xv.x + xv.y*xv.y + xv.z*xv.z + xv.w*xv.w;
  #pragma unroll
  for (int o = 32; o > 0; o >>= 1) ss += __shfl_down(ss, o);
  __shared__ float s_ss[4];
  __shared__ float s_p[4][8];
  if ((tid & 63) == 0) s_ss[tid >> 6] = ss;
  __syncthreads();
  const float tot = s_ss[0] + s_ss[1] + s_ss[2] + s_ss[3];
  const float inv = rsqrtf(tot * (1.0f / DD) + 1.1920929e-7f);
  const float4 nv = ((const float4*)nw)[tid];
  float4 xnv;
  xnv.x = xv.x*inv*nv.x; xnv.y = xv.y*inv*nv.y;
  xnv.z = xv.z*inv*nv.z; xnv.w = xv.w*inv*nv.w;
  ushort4 bv; bv.x = f2bf(xnv.x); bv.y = f2bf(xnv.y); bv.z = f2bf(xnv.z); bv.w = f2bf(xnv.w);
  ((ushort4*)(xn + (size_t)t * DD))[tid] = bv;
  float p[8];
  #pragma unroll
  for (int e = 0; e < 8; e++){
    const float4 g = ((const float4*)(gw + e * DD))[tid];
    p[e] = xnv.x*g.x + xnv.y*g.y + xnv.z*g.z + xnv.w*g.w;
  }
  #pragma unroll
  for (int e = 0; e < 8; e++){
    #pragma unroll
    for (int o = 32; o > 0; o >>= 1) p[e] += __shfl_down(p[e], o);
  }
  if ((tid & 63) == 0){
    #pragma unroll
    for (int e = 0; e < 8; e++) s_p[tid >> 6][e] = p[e];
  }
  __syncthreads();
  if (tid == 0){
    float lg[8], pr[8];
    #pragma unroll
    for (int e = 0; e < 8; e++) lg[e] = s_p[0][e] + s_p[1][e] + s_p[2][e] + s_p[3][e];
    float mx = lg[0];
    for (int e = 1; e < 8; e++) mx = fmaxf(mx, lg[e]);
    float sum = 0.f;
    for (int e = 0; e < 8; e++){ pr[e] = __expf(lg[e] - mx); sum += pr[e]; }
    const float is = 1.f / sum;
    for (int e = 0; e < 8; e++) pr[e] *= is;
    #pragma unroll
    for (int e = 0; e < 8; e++) probbuf[t * 8 + e] = pr[e];
    int e1 = 0;
    for (int e = 1; e < 8; e++) if (pr[e] > pr[e1]) e1 = e;       // first max (tie: lower idx)
    int e2 = (e1 == 0) ? 1 : 0;
    for (int e = 0; e < 8; e++) if (e != e1 && e != e2 && pr[e] > pr[e2]) e2 = e;
    const float wsum = fmaxf(pr[e1] + pr[e2], 1e-6f);
    topk_id[2*t] = e1; topk_id[2*t+1] = e2;
    topk_w[2*t] = pr[e1] / wsum; topk_w[2*t+1] = pr[e2] / wsum;
  }
}

// ------- single-block: counts, bases, lb loss, deterministic slot assignment ----
__global__ __launch_bounds__(256) void k_stats(
    const int* __restrict__ topk_id, const float* __restrict__ topk_w,
    const float* __restrict__ probbuf,
    int* __restrict__ counts, int* __restrict__ bases,
    int* __restrict__ slots_of, int* __restrict__ tok_of,
    float* __restrict__ slot_w,
    float* __restrict__ lb_out)
{
  const int tid = threadIdx.x;
  __shared__ int s_scan[256][8];
  __shared__ int s_base[8];

  int ids[16];
  int lc[8] = {}, lc1[8] = {};
  float lsp[8] = {};
  #pragma unroll
  for (int j = 0; j < 8; j++){
    const int t = tid * 8 + j;
    const int e1 = topk_id[2*t], e2 = topk_id[2*t+1];
    ids[2*j] = e1; ids[2*j+1] = e2;
    lc[e1]++; lc[e2]++; lc1[e1]++;
    const float4 p0 = ((const float4*)(probbuf + t * 8))[0];
    const float4 p1 = ((const float4*)(probbuf + t * 8))[1];
    lsp[0] += p0.x; lsp[1] += p0.y; lsp[2] += p0.z; lsp[3] += p0.w;
    lsp[4] += p1.x; lsp[5] += p1.y; lsp[6] += p1.z; lsp[7] += p1.w;
  }
  #pragma unroll
  for (int e = 0; e < 8; e++) s_scan[tid][e] = lc[e];
  __syncthreads();
  for (int off = 1; off < 256; off <<= 1){
    int v[8];
    if (tid >= off){
      #pragma unroll
      for (int e = 0; e < 8; e++) v[e] = s_scan[tid - off][e];
    }
    __syncthreads();
    if (tid >= off){
      #pragma unroll
      for (int e = 0; e < 8; e++) s_scan[tid][e] += v[e];
    }
    __syncthreads();
  }
  int   rc1[8]; float rsp[8];
  #pragma unroll
  for (int e = 0; e < 8; e++){ rc1[e] = lc1[e]; rsp[e] = lsp[e]; }
  #pragma unroll
  for (int e = 0; e < 8; e++){
    #pragma unroll
    for (int o = 32; o > 0; o >>= 1){
      rc1[e] += __shfl_down(rc1[e], o);
      rsp[e] += __shfl_down(rsp[e], o);
    }
  }
  __shared__ int   s_c1[4][8];
  __shared__ float s_sp[4][8];
  if ((tid & 63) == 0){
    const int w = tid >> 6;
    #pragma unroll
    for (int e = 0; e < 8; e++){ s_c1[w][e] = rc1[e]; s_sp[w][e] = rsp[e]; }
  }
  __syncthreads();
  if (tid == 0){
    int b = 0; float lb = 0.f;
    for (int e = 0; e < 8; e++){
      const int tot = s_scan[255][e];
      counts[e] = tot; bases[e] = b; s_base[e] = b; b += tot;
      const int   c1 = s_c1[0][e] + s_c1[1][e] + s_c1[2][e] + s_c1[3][e];
      const float sp = s_sp[0][e] + s_sp[1][e] + s_sp[2][e] + s_sp[3][e];
      lb += (float)c1 * sp;
    }
    lb_out[0] = 8.f * lb * (1.f / ((float)T_TOK * (float)T_TOK));
  }
  __syncthreads();
  int rank[8];
  #pragma unroll
  for (int e = 0; e < 8; e++) rank[e] = s_scan[tid][e] - lc[e];   // exclusive prefix
  #pragma unroll
  for (int j = 0; j < 8; j++){
    const int t = tid * 8 + j;
    #pragma unroll
    for (int k = 0; k < 2; k++){
      const int e = ids[2*j + k];
      const int slot = s_base[e] + rank[e]++;
      slots_of[2*t + k] = slot;
      tok_of[slot] = t;
      slot_w[slot] = topk_w[2*t + k];
    }
  }
}

// -------- grouped GEMM, 128x64 tile, deep pipeline + XCD-SPREAD mapping -------
// r5 post-mortem: three schedules (2-phase small/big tile, counted-vmcnt ring)
// all sit at ~2us/K-step, ~10% MfmaUtil, ~7.5 TB/s memory-system traffic. The
// invariant wall is OUTSIDE the CU: e = blockIdx&7 pinned every block of expert
// e onto XCD e (bid%8 round-robin), so each expert's whole weight stream (8MB
// fp32 through a 4MB L2, evicting A -> re-fetch) funnels through ONE XCD
// fabric port (~1 TB/s) == the observed ~70us. Fix: decode (e,nt,ms,ks) so
// each expert's panels spread across all 8 XCDs, while the 4 ms-blocks that
// share one B-panel stay on the SAME XCD and launch-adjacent (panel pulled
// over the fabric once): q=bid&7 -> nt = q + 8j; within an XCD, ms fastest,
// e slowest. Kernel body identical to r5 (verified): 3-deep LDS ring,
// s_waitcnt vmcnt(4) counted waits, all-GLDS staging, r3-verified swizzles.
// MODE 0: C = silu(xn[tok_of[slot]] @ w1^T) -> bf16 Hg
// MODE 1: split-K ks=2; C = partial(Hg @ w2^T) -> bf16 Og[ks]
template<int KD, int NDIM, int MODE>
__global__ __launch_bounds__(256, 3) void k_gemm(
    const unsigned short* __restrict__ Ag,
    const float* __restrict__ Bw,
    const int* __restrict__ counts, const int* __restrict__ bases,
    const int* __restrict__ tok_of,
    unsigned short* __restrict__ Cout)
{
  const int q = blockIdx.x & 7;       // XCD slot (bid % 8 round-robin)
  const int s = blockIdx.x >> 3;      // 0..127 within-XCD sequence
  int e, nt, ms, kbase; size_t poff;
  if (MODE == 0){
    ms = s & 3;                       // ms fastest: panel's 4 readers adjacent
    const int j = (s >> 2) & 3;       // nt = q + 8j : expert spread over XCDs
    e = s >> 4;                       // e slowest: A-panel locality per XCD
    nt = q + 8 * j; kbase = 0; poff = 0;
  } else {
    ms = s & 3;
    const int j  = (s >> 2) & 1;
    const int ks = (s >> 3) & 1;
    e = s >> 4;
    nt = q + 8 * j; kbase = ks * 1024;
    poff = (size_t)ks * SLOTPAD * NDIM;
  }
  const int M = counts[e];
  if (M == 0) return;
  const int sbase = bases[e];

  __shared__ __align__(16) unsigned short As[3][128 * 32];   // 3 x 8KB bf16
  __shared__ __align__(16) float          Bsf[3][64 * 32];   // 3 x 8KB fp32

  const int tid = threadIdx.x;
  const int l = tid & 63;
  const int w = tid >> 6;
  const int wm = (w >> 1) * 64, wn = (w & 1) * 32;
  const int lrow = l & 15, lq = l >> 4;

  // A staging: 512 chunks of 16B (4/row), 2/thread, source-swizzled
  const int ar0 = tid >> 2, ar1 = (tid + 256) >> 2, aq = tid & 3;
  const int akc0 = ((aq - (ar0 >> 1)) & 3) * 8;
  const int akc1 = ((aq - (ar1 >> 1)) & 3) * 8;
  // B staging: 512 chunks of 16B (8/row of 32 floats); thread handles physical
  // chunks tid (rows 0..31) and tid+256 (rows 32..63); same source offset.
  const int br0 = tid >> 3;
  const int bq  = tid & 7;
  const int bkc = ((bq - br0) & 7) * 4;

  const float* bsrc0 = Bw + (size_t)e * NDIM * KD + (size_t)(nt * 64 + br0) * KD + kbase + bkc;
  const float* bsrc1 = bsrc0 + (size_t)32 * KD;   // row br0+32, same swizzle mod 8

#define STAGE_TILE(SLOT, KO) do { \
      GLDS(arow0 + (KO), As[SLOT] + tid * 8); \
      GLDS(arow1 + (KO), As[SLOT] + (tid + 256) * 8); \
      GLDS(bsrc0 + (KO), Bsf[SLOT] + tid * 4); \
      GLDS(bsrc1 + (KO), Bsf[SLOT] + (tid + 256) * 4); \
    } while (0)

#define KSTEP(CB) do { \
      bf16x8 af[4], bfv[2]; \
      _Pragma("unroll") \
      for (int mi = 0; mi < 4; mi++){ \
        const int row = wm + mi * 16 + lrow; \
        const int p = (lq + (row >> 1)) & 3; \
        af[mi] = *(const bf16x8*)(As[CB] + row * 32 + p * 8); \
      } \
      _Pragma("unroll") \
      for (int ni = 0; ni < 2; ni++){ \
        const int row = wn + ni * 16 + lrow; \
        const int pp0 = (2 * lq + row) & 7; \
        const int pp1 = (2 * lq + 1 + row) & 7; \
        const float4 u0 = *(const float4*)(Bsf[CB] + row * 32 + pp0 * 4); \
        const float4 u1 = *(const float4*)(Bsf[CB] + row * 32 + pp1 * 4); \
        floatx8 uf; \
        uf[0]=u0.x; uf[1]=u0.y; uf[2]=u0.z; uf[3]=u0.w; \
        uf[4]=u1.x; uf[5]=u1.y; uf[6]=u1.z; uf[7]=u1.w; \
        bfv[ni] = __builtin_convertvector(uf, bf16x8); \
      } \
      _Pragma("unroll") \
      for (int mi = 0; mi < 4; mi++) \
        _Pragma("unroll") \
        for (int ni = 0; ni < 2; ni++) \
          acc[mi][ni] = __builtin_amdgcn_mfma_f32_16x16x32_bf16(af[mi], bfv[ni], acc[mi][ni], 0, 0, 0); \
    } while (0)

  for (int mt = ms; mt * 128 < M; mt += 4){
    const unsigned short *arow0, *arow1;
    {
      const int v0 = min(mt * 128 + ar0, M - 1);
      const int v1 = min(mt * 128 + ar1, M - 1);
      const int r0 = (MODE == 0) ? tok_of[sbase + v0] : (sbase + v0);
      const int r1 = (MODE == 0) ? tok_of[sbase + v1] : (sbase + v1);
      arow0 = Ag + (size_t)r0 * KD + kbase + akc0;
      arow1 = Ag + (size_t)r1 * KD + kbase + akc1;
    }

    floatx4 acc[4][2] = {};

    // prologue: tiles 0 and 1 in flight
    STAGE_TILE(0, 0);
    STAGE_TILE(1, 32);

    // main loop: iterations 0..29 stage tile kt+2; tiles kt+1 stay in flight
    #pragma unroll 3
    for (int kt = 0; kt < 30; kt++){
      asm volatile("s_waitcnt vmcnt(4)" ::: "memory");   // tile kt complete
      __builtin_amdgcn_sched_barrier(0);
      __builtin_amdgcn_s_barrier();
      __builtin_amdgcn_sched_barrier(0);
      const int cur = kt % 3;
      const int s2 = (kt + 2) % 3;
      STAGE_TILE(s2, (kt + 2) * 32);
      KSTEP(cur);
    }
    // kt = 30 (tile 31 still in flight)
    asm volatile("s_waitcnt vmcnt(4)" ::: "memory");
    __builtin_amdgcn_sched_barrier(0);
    __builtin_amdgcn_s_barrier();
    __builtin_amdgcn_sched_barrier(0);
    KSTEP(0);
    // kt = 31 (drain)
    asm volatile("s_waitcnt vmcnt(0)" ::: "memory");
    __builtin_amdgcn_sched_barrier(0);
    __builtin_amdgcn_s_barrier();
    __builtin_amdgcn_sched_barrier(0);
    KSTEP(1);

    // epilogue: C/D layout col = lane&15, row = (lane>>4)*4 + r
    const int rb = lq * 4;
    #pragma unroll
    for (int mi = 0; mi < 4; mi++){
      #pragma unroll
      for (int r = 0; r < 4; r++){
        const int row = mt * 128 + wm + mi * 16 + rb + r;
        if (row < M){
          #pragma unroll
          for (int ni = 0; ni < 2; ni++){
            const int col = nt * 64 + wn + ni * 16 + lrow;
            const float v = acc[mi][ni][r];
            if (MODE == 0){
              const float s2v = v / (1.f + __expf(-v));   // silu
              Cout[(size_t)(sbase + row) * NDIM + col] = f2bf(s2v);
            } else {
              Cout[poff + (size_t)(sbase + row) * NDIM + col] = f2bf(v);
            }
          }
        }
      }
    }
    __syncthreads();   // protect buffer reuse across mt-tiles
  }
#undef STAGE_TILE
#undef KSTEP
}

// ------- residual combine: out = x + sc*(w0*(p0a+p0b) + w1*(p1a+p1b)) ----------
__global__ __launch_bounds__(256) void k_combine(
    const float* __restrict__ x, const unsigned short* __restrict__ Og,
    const int* __restrict__ slots_of, const float* __restrict__ slot_w,
    const float* __restrict__ scale,
    float* __restrict__ out)
{
  const int i = blockIdx.x * 256 + threadIdx.x;   // over T*D/8
  const int t = i >> 7;
  const int j = i & 127;
  const int s0 = slots_of[2*t], s1 = slots_of[2*t+1];
  const float w0 = slot_w[s0], w1 = slot_w[s1];
  const ushort8 a0 = ((const ushort8*)(Og + (size_t)s0 * DD))[j];
  const ushort8 a1 = ((const ushort8*)(Og + (size_t)SLOTPAD * DD + (size_t)s0 * DD))[j];
  const ushort8 b0 = ((const ushort8*)(Og + (size_t)s1 * DD))[j];
  const ushort8 b1 = ((const ushort8*)(Og + (size_t)SLOTPAD * DD + (size_t)s1 * DD))[j];
  const float4 x0 = ((const float4*)(x + (size_t)t * DD))[2*j];
  const float4 x1 = ((const float4*)(x + (size_t)t * DD))[2*j + 1];
  const float sc = 1.f / (1.f + __expf(-scale[0]));
  float o[8];
  #pragma unroll
  for (int q = 0; q < 8; q++)
    o[q] = sc * (w0 * (bf2f(a0[q]) + bf2f(a1[q])) + w1 * (bf2f(b0[q]) + bf2f(b1[q])));
  float4 o0, o1;
  o0.x = x0.x + o[0]; o0.y = x0.y + o[1]; o0.z = x0.z + o[2]; o0.w = x0.w + o[3];
  o1.x = x1.x + o[4]; o1.y = x1.y + o[5]; o1.z = x1.z + o[6]; o1.w = x1.w + o[7];
  ((float4*)(out + (size_t)t * DD))[2*j] = o0;
  ((float4*)(out + (size_t)t * DD))[2*j + 1] = o1;
}

extern "C" void kernel_launch(void* const* d_in, const int* in_sizes, int n_in,
                              void* d_out, int out_size, void* d_ws, size_t ws_size,
                              hipStream_t stream)
{
  const float* x     = (const float*)d_in[0];   // [2,1024,1024]
  const float* gw    = (const float*)d_in[1];   // [8,1024]
  const float* w1    = (const float*)d_in[2];   // [8,2048,1024]
  const float* w2    = (const float*)d_in[3];   // [8,1024,2048]
  const float* nw    = (const float*)d_in[4];   // [1024]
  const float* scale = (const float*)d_in[5];   // [1]
  float* out = (float*)d_out;                   // 2097152 + 1 (lb loss)

  char* ws = (char*)d_ws;
  int*   counts  = (int*)(ws + 0);
  int*   bases   = (int*)(ws + 64);
  int*   topk_id = (int*)(ws + 1024);            // 16 KB
  float* topk_w  = (float*)(ws + 20480);         // 16 KB
  int*   slots_of= (int*)(ws + 40960);           // 16 KB
  float* slot_w  = (float*)(ws + 61440);         // 16.5 KB
  int*   tok_of  = (int*)(ws + 81920);           // 16 KB
  float* probbuf = (float*)(ws + 102400);        // 64 KB
  unsigned short* xn  = (unsigned short*)(ws + 262144);            // 4 MB
  unsigned short* Hg  = xn + (size_t)T_TOK * DD;                   // 17.3 MB
  unsigned short* Og  = Hg + (size_t)SLOTPAD * FF;                 // 2x 8.65 MB partials

  k_rms_router<<<T_TOK, 256, 0, stream>>>(x, gw, nw, xn, topk_id, topk_w, probbuf);
  k_stats<<<1, 256, 0, stream>>>(topk_id, topk_w, probbuf, counts, bases,
                                 slots_of, tok_of, slot_w, out + (size_t)T_TOK * DD);
  k_gemm<1024, 2048, 0><<<EE * 4 * 32, 256, 0, stream>>>(xn, w1, counts, bases, tok_of, Hg);
  k_gemm<2048, 1024, 1><<<EE * 4 * 16 * 2, 256, 0, stream>>>(Hg, w2, counts, bases, nullptr, Og);
  k_combine<<<T_TOK * DD / 8 / 256, 256, 0, stream>>>(x, Og, slots_of, slot_w, scale, out);
}

// Round 7
// 281.596 us; speedup vs baseline: 1.1089x; 1.1089x over previous
//
#include <hip/hip_runtime.h>
#include <stdint.h>

#define T_TOK 2048
#define DD 1024
#define EE 8
#define FF 2048
#define NSLOT 4096     // T*K
#define SLOTPAD 4224   // NSLOT + 128 pad rows
#define GEMM_GRID 1280 // >= worst-case total tiles (<=1248) in both modes

typedef __attribute__((ext_vector_type(8))) __bf16 bf16x8;
typedef __attribute__((ext_vector_type(4))) float floatx4;
typedef __attribute__((ext_vector_type(8))) float floatx8;
typedef __attribute__((ext_vector_type(8))) unsigned short ushort8;

__device__ __forceinline__ unsigned short f2bf(float f){
  union { float f; unsigned u; } v; v.f = f;
  unsigned r = v.u + 0x7fffu + ((v.u >> 16) & 1u);
  return (unsigned short)(r >> 16);
}
__device__ __forceinline__ float bf2f(unsigned short h){
  union { unsigned u; float f; } v; v.u = (unsigned)h << 16; return v.f;
}

#define GLDS(src, dst) __builtin_amdgcn_global_load_lds( \
    (__attribute__((address_space(1))) unsigned int*)(src), \
    (__attribute__((address_space(3))) unsigned int*)(dst), 16, 0, 0)

// ---------------- RMSNorm + router (one block per token, NO global atomics) ----
__global__ __launch_bounds__(256) void k_rms_router(
    const float* __restrict__ x, const float* __restrict__ gw,
    const float* __restrict__ nw,
    unsigned short* __restrict__ xn,
    int* __restrict__ topk_id, float* __restrict__ topk_w,
    float* __restrict__ probbuf)
{
  const int t = blockIdx.x, tid = threadIdx.x;
  const float4 xv = ((const float4*)(x + (size_t)t * DD))[tid];
  float ss = xv.x*xv.x + xv.y*xv.y + xv.z*xv.z + xv.w*xv.w;
  #pragma unroll
  for (int o = 32; o > 0; o >>= 1) ss += __shfl_down(ss, o);
  __shared__ float s_ss[4];
  __shared__ float s_p[4][8];
  if ((tid & 63) == 0) s_ss[tid >> 6] = ss;
  __syncthreads();
  const float tot = s_ss[0] + s_ss[1] + s_ss[2] + s_ss[3];
  const float inv = rsqrtf(tot * (1.0f / DD) + 1.1920929e-7f);
  const float4 nv = ((const float4*)nw)[tid];
  float4 xnv;
  xnv.x = xv.x*inv*nv.x; xnv.y = xv.y*inv*nv.y;
  xnv.z = xv.z*inv*nv.z; xnv.w = xv.w*inv*nv.w;
  ushort4 bv; bv.x = f2bf(xnv.x); bv.y = f2bf(xnv.y); bv.z = f2bf(xnv.z); bv.w = f2bf(xnv.w);
  ((ushort4*)(xn + (size_t)t * DD))[tid] = bv;
  float p[8];
  #pragma unroll
  for (int e = 0; e < 8; e++){
    const float4 g = ((const float4*)(gw + e * DD))[tid];
    p[e] = xnv.x*g.x + xnv.y*g.y + xnv.z*g.z + xnv.w*g.w;
  }
  #pragma unroll
  for (int e = 0; e < 8; e++){
    #pragma unroll
    for (int o = 32; o > 0; o >>= 1) p[e] += __shfl_down(p[e], o);
  }
  if ((tid & 63) == 0){
    #pragma unroll
    for (int e = 0; e < 8; e++) s_p[tid >> 6][e] = p[e];
  }
  __syncthreads();
  if (tid == 0){
    float lg[8], pr[8];
    #pragma unroll
    for (int e = 0; e < 8; e++) lg[e] = s_p[0][e] + s_p[1][e] + s_p[2][e] + s_p[3][e];
    float mx = lg[0];
    for (int e = 1; e < 8; e++) mx = fmaxf(mx, lg[e]);
    float sum = 0.f;
    for (int e = 0; e < 8; e++){ pr[e] = __expf(lg[e] - mx); sum += pr[e]; }
    const float is = 1.f / sum;
    for (int e = 0; e < 8; e++) pr[e] *= is;
    #pragma unroll
    for (int e = 0; e < 8; e++) probbuf[t * 8 + e] = pr[e];
    int e1 = 0;
    for (int e = 1; e < 8; e++) if (pr[e] > pr[e1]) e1 = e;       // first max (tie: lower idx)
    int e2 = (e1 == 0) ? 1 : 0;
    for (int e = 0; e < 8; e++) if (e != e1 && e != e2 && pr[e] > pr[e2]) e2 = e;
    const float wsum = fmaxf(pr[e1] + pr[e2], 1e-6f);
    topk_id[2*t] = e1; topk_id[2*t+1] = e2;
    topk_w[2*t] = pr[e1] / wsum; topk_w[2*t+1] = pr[e2] / wsum;
  }
}

// ------- single-block: counts, bases, lb loss, slot assignment, tile prefix ----
__global__ __launch_bounds__(256) void k_stats(
    const int* __restrict__ topk_id, const float* __restrict__ topk_w,
    const float* __restrict__ probbuf,
    int* __restrict__ counts, int* __restrict__ bases,
    int* __restrict__ tile_base,
    int* __restrict__ slots_of, int* __restrict__ tok_of,
    float* __restrict__ slot_w,
    float* __restrict__ lb_out)
{
  const int tid = threadIdx.x;
  __shared__ int s_scan[256][8];
  __shared__ int s_base[8];

  int ids[16];
  int lc[8] = {}, lc1[8] = {};
  float lsp[8] = {};
  #pragma unroll
  for (int j = 0; j < 8; j++){
    const int t = tid * 8 + j;
    const int e1 = topk_id[2*t], e2 = topk_id[2*t+1];
    ids[2*j] = e1; ids[2*j+1] = e2;
    lc[e1]++; lc[e2]++; lc1[e1]++;
    const float4 p0 = ((const float4*)(probbuf + t * 8))[0];
    const float4 p1 = ((const float4*)(probbuf + t * 8))[1];
    lsp[0] += p0.x; lsp[1] += p0.y; lsp[2] += p0.z; lsp[3] += p0.w;
    lsp[4] += p1.x; lsp[5] += p1.y; lsp[6] += p1.z; lsp[7] += p1.w;
  }
  #pragma unroll
  for (int e = 0; e < 8; e++) s_scan[tid][e] = lc[e];
  __syncthreads();
  for (int off = 1; off < 256; off <<= 1){
    int v[8];
    if (tid >= off){
      #pragma unroll
      for (int e = 0; e < 8; e++) v[e] = s_scan[tid - off][e];
    }
    __syncthreads();
    if (tid >= off){
      #pragma unroll
      for (int e = 0; e < 8; e++) s_scan[tid][e] += v[e];
    }
    __syncthreads();
  }
  int   rc1[8]; float rsp[8];
  #pragma unroll
  for (int e = 0; e < 8; e++){ rc1[e] = lc1[e]; rsp[e] = lsp[e]; }
  #pragma unroll
  for (int e = 0; e < 8; e++){
    #pragma unroll
    for (int o = 32; o > 0; o >>= 1){
      rc1[e] += __shfl_down(rc1[e], o);
      rsp[e] += __shfl_down(rsp[e], o);
    }
  }
  __shared__ int   s_c1[4][8];
  __shared__ float s_sp[4][8];
  if ((tid & 63) == 0){
    const int w = tid >> 6;
    #pragma unroll
    for (int e = 0; e < 8; e++){ s_c1[w][e] = rc1[e]; s_sp[w][e] = rsp[e]; }
  }
  __syncthreads();
  if (tid == 0){
    int b = 0; float lb = 0.f; int tb = 0;
    for (int e = 0; e < 8; e++){
      const int tot = s_scan[255][e];
      counts[e] = tot; bases[e] = b; s_base[e] = b; b += tot;
      tile_base[e] = tb; tb += (tot + 127) >> 7;     // ceil(M_e/128) tile-rows
      const int   c1 = s_c1[0][e] + s_c1[1][e] + s_c1[2][e] + s_c1[3][e];
      const float sp = s_sp[0][e] + s_sp[1][e] + s_sp[2][e] + s_sp[3][e];
      lb += (float)c1 * sp;
    }
    tile_base[8] = tb;
    lb_out[0] = 8.f * lb * (1.f / ((float)T_TOK * (float)T_TOK));
  }
  __syncthreads();
  int rank[8];
  #pragma unroll
  for (int e = 0; e < 8; e++) rank[e] = s_scan[tid][e] - lc[e];   // exclusive prefix
  #pragma unroll
  for (int j = 0; j < 8; j++){
    const int t = tid * 8 + j;
    #pragma unroll
    for (int k = 0; k < 2; k++){
      const int e = ids[2*j + k];
      const int slot = s_base[e] + rank[e]++;
      slots_of[2*t + k] = slot;
      tok_of[slot] = t;
      slot_w[slot] = topk_w[2*t + k];
    }
  }
}

// -------- grouped GEMM, 128x64 tile, deep pipeline, FLAT BALANCED TILE LIST ---
// r6 post-mortem: every round's (e,ms,nt) decode gave ms=0 blocks of M_e>512
// experts TWO mt-tiles while 87% of blocks did one -- the second half of each
// dispatch ran ~128 blocks on 256 CUs (~12% util for ~50% of the time). That
// invariant (not the schedule) is why all variants sat at ~10% MfmaUtil /
// ~25% occupancy. Fix: flat tile list. k_stats emits tile_base[] (prefix of
// ceil(M_e/128)); tiles/expert = T_e*32 in BOTH modes (M0: 32 nt; M1: 16nt x
// 2ks). Grid 1280 >= worst-case 1248; each block does EXACTLY ONE tile (or
// exits); HW backfill keeps CUs fed; max imbalance = 1 tile.
// Body identical to r5 (passed, best dur): 3-deep LDS ring, counted
// s_waitcnt vmcnt(4), all-GLDS staging, r3-verified swizzles.
// MODE 0: C = silu(xn[tok_of[slot]] @ w1^T) -> bf16 Hg
// MODE 1: split-K ks=2; C = partial(Hg @ w2^T) -> bf16 Og[ks]
template<int KD, int NDIM, int MODE>
__global__ __launch_bounds__(256, 3) void k_gemm(
    const unsigned short* __restrict__ Ag,
    const float* __restrict__ Bw,
    const int* __restrict__ counts, const int* __restrict__ bases,
    const int* __restrict__ tile_base,
    const int* __restrict__ tok_of,
    unsigned short* __restrict__ Cout)
{
  const int tile = blockIdx.x;
  if (tile >= tile_base[8] * 32) return;
  int e = 0;
  #pragma unroll
  for (int i = 0; i < 7; i++) e += (tile >= tile_base[i + 1] * 32) ? 1 : 0;
  const int local = tile - tile_base[e] * 32;
  const int mt = local >> 5;          // tile-row within expert
  const int q  = local & 31;
  int nt, kbase; size_t poff;
  if (MODE == 0){ nt = q; kbase = 0; poff = 0; }
  else { nt = q & 15; const int ks = q >> 4; kbase = ks * 1024;
         poff = (size_t)ks * SLOTPAD * NDIM; }
  const int M = counts[e];
  const int sbase = bases[e];

  __shared__ __align__(16) unsigned short As[3][128 * 32];   // 3 x 8KB bf16
  __shared__ __align__(16) float          Bsf[3][64 * 32];   // 3 x 8KB fp32

  const int tid = threadIdx.x;
  const int l = tid & 63;
  const int w = tid >> 6;
  const int wm = (w >> 1) * 64, wn = (w & 1) * 32;
  const int lrow = l & 15, lq = l >> 4;

  // A staging: 512 chunks of 16B (4/row), 2/thread, source-swizzled
  const int ar0 = tid >> 2, ar1 = (tid + 256) >> 2, aq = tid & 3;
  const int akc0 = ((aq - (ar0 >> 1)) & 3) * 8;
  const int akc1 = ((aq - (ar1 >> 1)) & 3) * 8;
  // B staging: 512 chunks of 16B (8/row of 32 floats); thread handles physical
  // chunks tid (rows 0..31) and tid+256 (rows 32..63); same source offset.
  const int br0 = tid >> 3;
  const int bq  = tid & 7;
  const int bkc = ((bq - br0) & 7) * 4;

  const float* bsrc0 = Bw + (size_t)e * NDIM * KD + (size_t)(nt * 64 + br0) * KD + kbase + bkc;
  const float* bsrc1 = bsrc0 + (size_t)32 * KD;   // row br0+32, same swizzle mod 8

  const unsigned short *arow0, *arow1;
  {
    const int v0 = min(mt * 128 + ar0, M - 1);
    const int v1 = min(mt * 128 + ar1, M - 1);
    const int r0 = (MODE == 0) ? tok_of[sbase + v0] : (sbase + v0);
    const int r1 = (MODE == 0) ? tok_of[sbase + v1] : (sbase + v1);
    arow0 = Ag + (size_t)r0 * KD + kbase + akc0;
    arow1 = Ag + (size_t)r1 * KD + kbase + akc1;
  }

#define STAGE_TILE(SLOT, KO) do { \
      GLDS(arow0 + (KO), As[SLOT] + tid * 8); \
      GLDS(arow1 + (KO), As[SLOT] + (tid + 256) * 8); \
      GLDS(bsrc0 + (KO), Bsf[SLOT] + tid * 4); \
      GLDS(bsrc1 + (KO), Bsf[SLOT] + (tid + 256) * 4); \
    } while (0)

#define KSTEP(CB) do { \
      bf16x8 af[4], bfv[2]; \
      _Pragma("unroll") \
      for (int mi = 0; mi < 4; mi++){ \
        const int row = wm + mi * 16 + lrow; \
        const int p = (lq + (row >> 1)) & 3; \
        af[mi] = *(const bf16x8*)(As[CB] + row * 32 + p * 8); \
      } \
      _Pragma("unroll") \
      for (int ni = 0; ni < 2; ni++){ \
        const int row = wn + ni * 16 + lrow; \
        const int pp0 = (2 * lq + row) & 7; \
        const int pp1 = (2 * lq + 1 + row) & 7; \
        const float4 u0 = *(const float4*)(Bsf[CB] + row * 32 + pp0 * 4); \
        const float4 u1 = *(const float4*)(Bsf[CB] + row * 32 + pp1 * 4); \
        floatx8 uf; \
        uf[0]=u0.x; uf[1]=u0.y; uf[2]=u0.z; uf[3]=u0.w; \
        uf[4]=u1.x; uf[5]=u1.y; uf[6]=u1.z; uf[7]=u1.w; \
        bfv[ni] = __builtin_convertvector(uf, bf16x8); \
      } \
      _Pragma("unroll") \
      for (int mi = 0; mi < 4; mi++) \
        _Pragma("unroll") \
        for (int ni = 0; ni < 2; ni++) \
          acc[mi][ni] = __builtin_amdgcn_mfma_f32_16x16x32_bf16(af[mi], bfv[ni], acc[mi][ni], 0, 0, 0); \
    } while (0)

  floatx4 acc[4][2] = {};

  // prologue: tiles 0 and 1 in flight
  STAGE_TILE(0, 0);
  STAGE_TILE(1, 32);

  // main loop: iterations 0..29 stage tile kt+2; tiles kt+1 stay in flight
  #pragma unroll 3
  for (int kt = 0; kt < 30; kt++){
    asm volatile("s_waitcnt vmcnt(4)" ::: "memory");   // tile kt complete
    __builtin_amdgcn_sched_barrier(0);
    __builtin_amdgcn_s_barrier();
    __builtin_amdgcn_sched_barrier(0);
    const int cur = kt % 3;
    const int s2 = (kt + 2) % 3;
    STAGE_TILE(s2, (kt + 2) * 32);
    KSTEP(cur);
  }
  // kt = 30 (tile 31 still in flight)
  asm volatile("s_waitcnt vmcnt(4)" ::: "memory");
  __builtin_amdgcn_sched_barrier(0);
  __builtin_amdgcn_s_barrier();
  __builtin_amdgcn_sched_barrier(0);
  KSTEP(0);
  // kt = 31 (drain)
  asm volatile("s_waitcnt vmcnt(0)" ::: "memory");
  __builtin_amdgcn_sched_barrier(0);
  __builtin_amdgcn_s_barrier();
  __builtin_amdgcn_sched_barrier(0);
  KSTEP(1);

  // epilogue: C/D layout col = lane&15, row = (lane>>4)*4 + r
  const int rb = lq * 4;
  #pragma unroll
  for (int mi = 0; mi < 4; mi++){
    #pragma unroll
    for (int r = 0; r < 4; r++){
      const int row = mt * 128 + wm + mi * 16 + rb + r;
      if (row < M){
        #pragma unroll
        for (int ni = 0; ni < 2; ni++){
          const int col = nt * 64 + wn + ni * 16 + lrow;
          const float v = acc[mi][ni][r];
          if (MODE == 0){
            const float s2v = v / (1.f + __expf(-v));   // silu
            Cout[(size_t)(sbase + row) * NDIM + col] = f2bf(s2v);
          } else {
            Cout[poff + (size_t)(sbase + row) * NDIM + col] = f2bf(v);
          }
        }
      }
    }
  }
#undef STAGE_TILE
#undef KSTEP
}

// ------- residual combine: out = x + sc*(w0*(p0a+p0b) + w1*(p1a+p1b)) ----------
__global__ __launch_bounds__(256) void k_combine(
    const float* __restrict__ x, const unsigned short* __restrict__ Og,
    const int* __restrict__ slots_of, const float* __restrict__ slot_w,
    const float* __restrict__ scale,
    float* __restrict__ out)
{
  const int i = blockIdx.x * 256 + threadIdx.x;   // over T*D/8
  const int t = i >> 7;
  const int j = i & 127;
  const int s0 = slots_of[2*t], s1 = slots_of[2*t+1];
  const float w0 = slot_w[s0], w1 = slot_w[s1];
  const ushort8 a0 = ((const ushort8*)(Og + (size_t)s0 * DD))[j];
  const ushort8 a1 = ((const ushort8*)(Og + (size_t)SLOTPAD * DD + (size_t)s0 * DD))[j];
  const ushort8 b0 = ((const ushort8*)(Og + (size_t)s1 * DD))[j];
  const ushort8 b1 = ((const ushort8*)(Og + (size_t)SLOTPAD * DD + (size_t)s1 * DD))[j];
  const float4 x0 = ((const float4*)(x + (size_t)t * DD))[2*j];
  const float4 x1 = ((const float4*)(x + (size_t)t * DD))[2*j + 1];
  const float sc = 1.f / (1.f + __expf(-scale[0]));
  float o[8];
  #pragma unroll
  for (int q = 0; q < 8; q++)
    o[q] = sc * (w0 * (bf2f(a0[q]) + bf2f(a1[q])) + w1 * (bf2f(b0[q]) + bf2f(b1[q])));
  float4 o0, o1;
  o0.x = x0.x + o[0]; o0.y = x0.y + o[1]; o0.z = x0.z + o[2]; o0.w = x0.w + o[3];
  o1.x = x1.x + o[4]; o1.y = x1.y + o[5]; o1.z = x1.z + o[6]; o1.w = x1.w + o[7];
  ((float4*)(out + (size_t)t * DD))[2*j] = o0;
  ((float4*)(out + (size_t)t * DD))[2*j + 1] = o1;
}

extern "C" void kernel_launch(void* const* d_in, const int* in_sizes, int n_in,
                              void* d_out, int out_size, void* d_ws, size_t ws_size,
                              hipStream_t stream)
{
  const float* x     = (const float*)d_in[0];   // [2,1024,1024]
  const float* gw    = (const float*)d_in[1];   // [8,1024]
  const float* w1    = (const float*)d_in[2];   // [8,2048,1024]
  const float* w2    = (const float*)d_in[3];   // [8,1024,2048]
  const float* nw    = (const float*)d_in[4];   // [1024]
  const float* scale = (const float*)d_in[5];   // [1]
  float* out = (float*)d_out;                   // 2097152 + 1 (lb loss)

  char* ws = (char*)d_ws;
  int*   counts  = (int*)(ws + 0);
  int*   bases   = (int*)(ws + 64);
  int*   tilebase= (int*)(ws + 128);             // 9 ints
  int*   topk_id = (int*)(ws + 1024);            // 16 KB
  float* topk_w  = (float*)(ws + 20480);         // 16 KB
  int*   slots_of= (int*)(ws + 40960);           // 16 KB
  float* slot_w  = (float*)(ws + 61440);         // 16.5 KB
  int*   tok_of  = (int*)(ws + 81920);           // 16 KB
  float* probbuf = (float*)(ws + 102400);        // 64 KB
  unsigned short* xn  = (unsigned short*)(ws + 262144);            // 4 MB
  unsigned short* Hg  = xn + (size_t)T_TOK * DD;                   // 17.3 MB
  unsigned short* Og  = Hg + (size_t)SLOTPAD * FF;                 // 2x 8.65 MB partials

  k_rms_router<<<T_TOK, 256, 0, stream>>>(x, gw, nw, xn, topk_id, topk_w, probbuf);
  k_stats<<<1, 256, 0, stream>>>(topk_id, topk_w, probbuf, counts, bases, tilebase,
                                 slots_of, tok_of, slot_w, out + (size_t)T_TOK * DD);
  k_gemm<1024, 2048, 0><<<GEMM_GRID, 256, 0, stream>>>(xn, w1, counts, bases, tilebase, tok_of, Hg);
  k_gemm<2048, 1024, 1><<<GEMM_GRID, 256, 0, stream>>>(Hg, w2, counts, bases, tilebase, nullptr, Og);
  k_combine<<<T_TOK * DD / 8 / 256, 256, 0, stream>>>(x, Og, slots_of, slot_w, scale, out);
}

// Round 8
// 254.504 us; speedup vs baseline: 1.2269x; 1.1064x over previous
//
#include <hip/hip_runtime.h>
#include <stdint.h>

#define T_TOK 2048
#define DD 1024
#define EE 8
#define FF 2048
#define NSLOT 4096     // T*K
#define SLOTPAD 4224   // NSLOT + 128 pad rows
#define GEMM_GRID 768  // >= worst-case tile rows (32+7) * 16 tiles/row

typedef __attribute__((ext_vector_type(8))) __bf16 bf16x8;
typedef __attribute__((ext_vector_type(4))) float floatx4;
typedef __attribute__((ext_vector_type(8))) float floatx8;
typedef __attribute__((ext_vector_type(8))) unsigned short ushort8;

__device__ __forceinline__ unsigned short f2bf(float f){
  union { float f; unsigned u; } v; v.f = f;
  unsigned r = v.u + 0x7fffu + ((v.u >> 16) & 1u);
  return (unsigned short)(r >> 16);
}
__device__ __forceinline__ float bf2f(unsigned short h){
  union { unsigned u; float f; } v; v.u = (unsigned)h << 16; return v.f;
}

#define GLDS(src, dst) __builtin_amdgcn_global_load_lds( \
    (__attribute__((address_space(1))) unsigned int*)(src), \
    (__attribute__((address_space(3))) unsigned int*)(dst), 16, 0, 0)

// ---- RMSNorm + router (blocks 0..2047) + w1/w2 fp32->bf16 conv (rest) --------
// Conversion fused here: it is independent of everything else, fills the CUs
// alongside the light router blocks, and saves a separate launch. 16384 conv
// blocks x 2048 elems = 33.55M elems (w1 then w2).
__global__ __launch_bounds__(256) void k_rms_router(
    const float* __restrict__ x, const float* __restrict__ gw,
    const float* __restrict__ nw,
    const float* __restrict__ w1, const float* __restrict__ w2,
    unsigned short* __restrict__ xn,
    unsigned short* __restrict__ w1b, unsigned short* __restrict__ w2b,
    int* __restrict__ topk_id, float* __restrict__ topk_w,
    float* __restrict__ probbuf)
{
  const int tid = threadIdx.x;
  if (blockIdx.x >= T_TOK){
    const int cb = blockIdx.x - T_TOK;            // 0..16383
    const float* src; unsigned short* dst; size_t off;
    if (cb < 8192){ src = w1; dst = w1b; off = (size_t)cb * 2048 + tid * 8; }
    else          { src = w2; dst = w2b; off = (size_t)(cb - 8192) * 2048 + tid * 8; }
    const float4 u0 = ((const float4*)(src + off))[0];
    const float4 u1 = ((const float4*)(src + off))[1];
    floatx8 f;
    f[0]=u0.x; f[1]=u0.y; f[2]=u0.z; f[3]=u0.w;
    f[4]=u1.x; f[5]=u1.y; f[6]=u1.z; f[7]=u1.w;
    *(bf16x8*)(dst + off) = __builtin_convertvector(f, bf16x8);
    return;
  }
  const int t = blockIdx.x;
  const float4 xv = ((const float4*)(x + (size_t)t * DD))[tid];
  float ss = xv.x*xv.x + xv.y*xv.y + xv.z*xv.z + xv.w*xv.w;
  #pragma unroll
  for (int o = 32; o > 0; o >>= 1) ss += __shfl_down(ss, o);
  __shared__ float s_ss[4];
  __shared__ float s_p[4][8];
  if ((tid & 63) == 0) s_ss[tid >> 6] = ss;
  __syncthreads();
  const float tot = s_ss[0] + s_ss[1] + s_ss[2] + s_ss[3];
  const float inv = rsqrtf(tot * (1.0f / DD) + 1.1920929e-7f);
  const float4 nv = ((const float4*)nw)[tid];
  float4 xnv;
  xnv.x = xv.x*inv*nv.x; xnv.y = xv.y*inv*nv.y;
  xnv.z = xv.z*inv*nv.z; xnv.w = xv.w*inv*nv.w;
  ushort4 bv; bv.x = f2bf(xnv.x); bv.y = f2bf(xnv.y); bv.z = f2bf(xnv.z); bv.w = f2bf(xnv.w);
  ((ushort4*)(xn + (size_t)t * DD))[tid] = bv;
  float p[8];
  #pragma unroll
  for (int e = 0; e < 8; e++){
    const float4 g = ((const float4*)(gw + e * DD))[tid];
    p[e] = xnv.x*g.x + xnv.y*g.y + xnv.z*g.z + xnv.w*g.w;
  }
  #pragma unroll
  for (int e = 0; e < 8; e++){
    #pragma unroll
    for (int o = 32; o > 0; o >>= 1) p[e] += __shfl_down(p[e], o);
  }
  if ((tid & 63) == 0){
    #pragma unroll
    for (int e = 0; e < 8; e++) s_p[tid >> 6][e] = p[e];
  }
  __syncthreads();
  if (tid == 0){
    float lg[8], pr[8];
    #pragma unroll
    for (int e = 0; e < 8; e++) lg[e] = s_p[0][e] + s_p[1][e] + s_p[2][e] + s_p[3][e];
    float mx = lg[0];
    for (int e = 1; e < 8; e++) mx = fmaxf(mx, lg[e]);
    float sum = 0.f;
    for (int e = 0; e < 8; e++){ pr[e] = __expf(lg[e] - mx); sum += pr[e]; }
    const float is = 1.f / sum;
    for (int e = 0; e < 8; e++) pr[e] *= is;
    #pragma unroll
    for (int e = 0; e < 8; e++) probbuf[t * 8 + e] = pr[e];
    int e1 = 0;
    for (int e = 1; e < 8; e++) if (pr[e] > pr[e1]) e1 = e;       // first max (tie: lower idx)
    int e2 = (e1 == 0) ? 1 : 0;
    for (int e = 0; e < 8; e++) if (e != e1 && e != e2 && pr[e] > pr[e2]) e2 = e;
    const float wsum = fmaxf(pr[e1] + pr[e2], 1e-6f);
    topk_id[2*t] = e1; topk_id[2*t+1] = e2;
    topk_w[2*t] = pr[e1] / wsum; topk_w[2*t+1] = pr[e2] / wsum;
  }
}

// ------- single-block: counts, bases, lb loss, slot assignment, tile prefix ----
__global__ __launch_bounds__(256) void k_stats(
    const int* __restrict__ topk_id, const float* __restrict__ topk_w,
    const float* __restrict__ probbuf,
    int* __restrict__ counts, int* __restrict__ bases,
    int* __restrict__ tile_base,
    int* __restrict__ slots_of, int* __restrict__ tok_of,
    float* __restrict__ slot_w,
    float* __restrict__ lb_out)
{
  const int tid = threadIdx.x;
  __shared__ int s_scan[256][8];
  __shared__ int s_base[8];

  int ids[16];
  int lc[8] = {}, lc1[8] = {};
  float lsp[8] = {};
  #pragma unroll
  for (int j = 0; j < 8; j++){
    const int t = tid * 8 + j;
    const int e1 = topk_id[2*t], e2 = topk_id[2*t+1];
    ids[2*j] = e1; ids[2*j+1] = e2;
    lc[e1]++; lc[e2]++; lc1[e1]++;
    const float4 p0 = ((const float4*)(probbuf + t * 8))[0];
    const float4 p1 = ((const float4*)(probbuf + t * 8))[1];
    lsp[0] += p0.x; lsp[1] += p0.y; lsp[2] += p0.z; lsp[3] += p0.w;
    lsp[4] += p1.x; lsp[5] += p1.y; lsp[6] += p1.z; lsp[7] += p1.w;
  }
  #pragma unroll
  for (int e = 0; e < 8; e++) s_scan[tid][e] = lc[e];
  __syncthreads();
  for (int off = 1; off < 256; off <<= 1){
    int v[8];
    if (tid >= off){
      #pragma unroll
      for (int e = 0; e < 8; e++) v[e] = s_scan[tid - off][e];
    }
    __syncthreads();
    if (tid >= off){
      #pragma unroll
      for (int e = 0; e < 8; e++) s_scan[tid][e] += v[e];
    }
    __syncthreads();
  }
  int   rc1[8]; float rsp[8];
  #pragma unroll
  for (int e = 0; e < 8; e++){ rc1[e] = lc1[e]; rsp[e] = lsp[e]; }
  #pragma unroll
  for (int e = 0; e < 8; e++){
    #pragma unroll
    for (int o = 32; o > 0; o >>= 1){
      rc1[e] += __shfl_down(rc1[e], o);
      rsp[e] += __shfl_down(rsp[e], o);
    }
  }
  __shared__ int   s_c1[4][8];
  __shared__ float s_sp[4][8];
  if ((tid & 63) == 0){
    const int w = tid >> 6;
    #pragma unroll
    for (int e = 0; e < 8; e++){ s_c1[w][e] = rc1[e]; s_sp[w][e] = rsp[e]; }
  }
  __syncthreads();
  if (tid == 0){
    int b = 0; float lb = 0.f; int tb = 0;
    for (int e = 0; e < 8; e++){
      const int tot = s_scan[255][e];
      counts[e] = tot; bases[e] = b; s_base[e] = b; b += tot;
      tile_base[e] = tb; tb += (tot + 127) >> 7;     // ceil(M_e/128) tile-rows
      const int   c1 = s_c1[0][e] + s_c1[1][e] + s_c1[2][e] + s_c1[3][e];
      const float sp = s_sp[0][e] + s_sp[1][e] + s_sp[2][e] + s_sp[3][e];
      lb += (float)c1 * sp;
    }
    tile_base[8] = tb;
    lb_out[0] = 8.f * lb * (1.f / ((float)T_TOK * (float)T_TOK));
  }
  __syncthreads();
  int rank[8];
  #pragma unroll
  for (int e = 0; e < 8; e++) rank[e] = s_scan[tid][e] - lc[e];   // exclusive prefix
  #pragma unroll
  for (int j = 0; j < 8; j++){
    const int t = tid * 8 + j;
    #pragma unroll
    for (int k = 0; k < 2; k++){
      const int e = ids[2*j + k];
      const int slot = s_base[e] + rank[e]++;
      slots_of[2*t + k] = slot;
      tok_of[slot] = t;
      slot_w[slot] = topk_w[2*t + k];
    }
  }
}

// -------- grouped GEMM, 128x128 tile, all-bf16 GLDS, HALVED L3 TRAFFIC --------
// r7 post-mortem: the session invariant is staged-bytes/time ~= 7.5 TB/s (R3:
// 524 MB / 68us; R5: 524/76; R7: 524/74) with the ~180 MB working set
// L3-resident (FETCH ~50 MB). The GEMM is L3-BANDWIDTH-BOUND, not schedule-
// bound; MfmaUtil ~10% is the corollary (16 MFMA-cyc per 16KB staged at
// 7.5 TB/s). R4 halved traffic but fell to 2 latency-exposed blocks/CU.
// This kernel halves traffic while KEEPING R3's proven concurrency:
//  - weights pre-converted to bf16 (fused into k_rms_router)
//  - BN 64->128: A-rep 32->16, B bf16: per-GEMM traffic 524 -> 262 MB
//  - BM=128 BK=32, 4 waves x acc[4][4] (16 MFMA + 8 ds_read_b128 /wave/step)
//  - R3's exact 2-phase dbuf skeleton + verified chunk swizzle; LDS 32 KB ->
//    4 blocks/CU; whole ~640-block grid co-resident (flat tile list, r7).
// MODE 0: tile q=nt in [0,16); C = silu(xn[tok_of[slot]] @ w1b^T) -> bf16 Hg
// MODE 1: q -> nt in [0,8) x ks in [0,2) split-K; C = partial(Hg @ w2b^T) -> Og[ks]
template<int KD, int NDIM, int MODE>
__global__ __launch_bounds__(256, 4) void k_gemm(
    const unsigned short* __restrict__ Ag,
    const unsigned short* __restrict__ Bb,
    const int* __restrict__ counts, const int* __restrict__ bases,
    const int* __restrict__ tile_base,
    const int* __restrict__ tok_of,
    unsigned short* __restrict__ Cout)
{
  const int tile = blockIdx.x;
  if (tile >= tile_base[8] * 16) return;
  int e = 0;
  #pragma unroll
  for (int i = 0; i < 7; i++) e += (tile >= tile_base[i + 1] * 16) ? 1 : 0;
  const int local = tile - tile_base[e] * 16;
  const int mt = local >> 4;          // tile-row within expert
  const int q  = local & 15;
  int nt, kbase; size_t poff;
  if (MODE == 0){ nt = q; kbase = 0; poff = 0; }
  else { nt = q & 7; const int ks = q >> 3; kbase = ks * 1024;
         poff = (size_t)ks * SLOTPAD * NDIM; }
  const int M = counts[e];
  const int sbase = bases[e];

  __shared__ __align__(16) unsigned short As[2][128 * 32];   // 2 x 8KB bf16
  __shared__ __align__(16) unsigned short Bs[2][128 * 32];   // 2 x 8KB bf16

  const int tid = threadIdx.x;
  const int l = tid & 63;
  const int w = tid >> 6;
  const int wm = (w >> 1) * 64, wn = (w & 1) * 64;
  const int lrow = l & 15, lq = l >> 4;

  // staging: 512 chunks of 16B per operand (4/row of 32 bf16), 2/thread each.
  // chunk c: row c>>2, phys pos c&3 holds logical k-chunk (pos-(row>>1))&3;
  // source address carries the swizzle; LDS dest linear (lane-stride 16B).
  // rows c>>2 and (c+256)>>2 = +64 share the offset (64>>1 == 0 mod 4).
  const int cr = tid >> 2, cq = tid & 3;
  const int ckc = ((cq - (cr >> 1)) & 3) * 8;    // element offset (bf16)

  const unsigned short* brow0 = Bb + (size_t)e * NDIM * KD
                              + (size_t)(nt * 128 + cr) * KD + kbase + ckc;
  const unsigned short* brow1 = brow0 + (size_t)64 * KD;

  const unsigned short *arow0, *arow1;
  {
    const int v0 = min(mt * 128 + cr, M - 1);
    const int v1 = min(mt * 128 + cr + 64, M - 1);
    const int r0 = (MODE == 0) ? tok_of[sbase + v0] : (sbase + v0);
    const int r1 = (MODE == 0) ? tok_of[sbase + v1] : (sbase + v1);
    arow0 = Ag + (size_t)r0 * KD + kbase + ckc;
    arow1 = Ag + (size_t)r1 * KD + kbase + ckc;
  }

  floatx4 acc[4][4] = {};

  // prologue: K-step 0 into buffer 0
  GLDS(arow0, As[0] + tid * 8);
  GLDS(arow1, As[0] + (tid + 256) * 8);
  GLDS(brow0, Bs[0] + tid * 8);
  GLDS(brow1, Bs[0] + (tid + 256) * 8);

  for (int kk = 0; kk < 32; kk++){
    const int cur = kk & 1, nxt = cur ^ 1;
    __syncthreads();                         // buf[cur] ready; buf[nxt] free
    if (kk < 31){
      const int ko = (kk + 1) * 32;
      GLDS(arow0 + ko, As[nxt] + tid * 8);
      GLDS(arow1 + ko, As[nxt] + (tid + 256) * 8);
      GLDS(brow0 + ko, Bs[nxt] + tid * 8);
      GLDS(brow1 + ko, Bs[nxt] + (tid + 256) * 8);
    }
    bf16x8 af[4], bfv[4];
    #pragma unroll
    for (int mi = 0; mi < 4; mi++){
      const int row = wm + mi * 16 + lrow;
      const int p = (lq + (row >> 1)) & 3;
      af[mi] = *(const bf16x8*)(As[cur] + row * 32 + p * 8);
    }
    #pragma unroll
    for (int ni = 0; ni < 4; ni++){
      const int row = wn + ni * 16 + lrow;
      const int p = (lq + (row >> 1)) & 3;
      bfv[ni] = *(const bf16x8*)(Bs[cur] + row * 32 + p * 8);
    }
    #pragma unroll
    for (int mi = 0; mi < 4; mi++)
      #pragma unroll
      for (int ni = 0; ni < 4; ni++)
        acc[mi][ni] = __builtin_amdgcn_mfma_f32_16x16x32_bf16(af[mi], bfv[ni], acc[mi][ni], 0, 0, 0);
  }

  // epilogue: C/D layout col = lane&15, row = (lane>>4)*4 + r
  const int rb = lq * 4;
  #pragma unroll
  for (int mi = 0; mi < 4; mi++){
    #pragma unroll
    for (int r = 0; r < 4; r++){
      const int row = mt * 128 + wm + mi * 16 + rb + r;
      if (row < M){
        #pragma unroll
        for (int ni = 0; ni < 4; ni++){
          const int col = nt * 128 + wn + ni * 16 + lrow;
          const float v = acc[mi][ni][r];
          if (MODE == 0){
            const float s2v = v / (1.f + __expf(-v));   // silu
            Cout[(size_t)(sbase + row) * NDIM + col] = f2bf(s2v);
          } else {
            Cout[poff + (size_t)(sbase + row) * NDIM + col] = f2bf(v);
          }
        }
      }
    }
  }
}

// ------- residual combine: out = x + sc*(w0*(p0a+p0b) + w1*(p1a+p1b)) ----------
__global__ __launch_bounds__(256) void k_combine(
    const float* __restrict__ x, const unsigned short* __restrict__ Og,
    const int* __restrict__ slots_of, const float* __restrict__ slot_w,
    const float* __restrict__ scale,
    float* __restrict__ out)
{
  const int i = blockIdx.x * 256 + threadIdx.x;   // over T*D/8
  const int t = i >> 7;
  const int j = i & 127;
  const int s0 = slots_of[2*t], s1 = slots_of[2*t+1];
  const float w0 = slot_w[s0], w1 = slot_w[s1];
  const ushort8 a0 = ((const ushort8*)(Og + (size_t)s0 * DD))[j];
  const ushort8 a1 = ((const ushort8*)(Og + (size_t)SLOTPAD * DD + (size_t)s0 * DD))[j];
  const ushort8 b0 = ((const ushort8*)(Og + (size_t)s1 * DD))[j];
  const ushort8 b1 = ((const ushort8*)(Og + (size_t)SLOTPAD * DD + (size_t)s1 * DD))[j];
  const float4 x0 = ((const float4*)(x + (size_t)t * DD))[2*j];
  const float4 x1 = ((const float4*)(x + (size_t)t * DD))[2*j + 1];
  const float sc = 1.f / (1.f + __expf(-scale[0]));
  float o[8];
  #pragma unroll
  for (int q = 0; q < 8; q++)
    o[q] = sc * (w0 * (bf2f(a0[q]) + bf2f(a1[q])) + w1 * (bf2f(b0[q]) + bf2f(b1[q])));
  float4 o0, o1;
  o0.x = x0.x + o[0]; o0.y = x0.y + o[1]; o0.z = x0.z + o[2]; o0.w = x0.w + o[3];
  o1.x = x1.x + o[4]; o1.y = x1.y + o[5]; o1.z = x1.z + o[6]; o1.w = x1.w + o[7];
  ((float4*)(out + (size_t)t * DD))[2*j] = o0;
  ((float4*)(out + (size_t)t * DD))[2*j + 1] = o1;
}

extern "C" void kernel_launch(void* const* d_in, const int* in_sizes, int n_in,
                              void* d_out, int out_size, void* d_ws, size_t ws_size,
                              hipStream_t stream)
{
  const float* x     = (const float*)d_in[0];   // [2,1024,1024]
  const float* gw    = (const float*)d_in[1];   // [8,1024]
  const float* w1    = (const float*)d_in[2];   // [8,2048,1024]
  const float* w2    = (const float*)d_in[3];   // [8,1024,2048]
  const float* nw    = (const float*)d_in[4];   // [1024]
  const float* scale = (const float*)d_in[5];   // [1]
  float* out = (float*)d_out;                   // 2097152 + 1 (lb loss)

  char* ws = (char*)d_ws;
  int*   counts  = (int*)(ws + 0);
  int*   bases   = (int*)(ws + 64);
  int*   tilebase= (int*)(ws + 128);             // 9 ints
  int*   topk_id = (int*)(ws + 1024);            // 16 KB
  float* topk_w  = (float*)(ws + 20480);         // 16 KB
  int*   slots_of= (int*)(ws + 40960);           // 16 KB
  float* slot_w  = (float*)(ws + 61440);         // 16.5 KB
  int*   tok_of  = (int*)(ws + 81920);           // 16 KB
  float* probbuf = (float*)(ws + 102400);        // 64 KB
  unsigned short* xn  = (unsigned short*)(ws + 262144);            // 4 MB
  unsigned short* Hg  = xn + (size_t)T_TOK * DD;                   // 17.3 MB
  unsigned short* Og  = Hg + (size_t)SLOTPAD * FF;                 // 2x 8.65 MB partials
  unsigned short* w1b = Og + (size_t)2 * SLOTPAD * DD;             // 33.55 MB bf16 w1
  unsigned short* w2b = w1b + (size_t)EE * FF * DD;                // 33.55 MB bf16 w2

  k_rms_router<<<T_TOK + 16384, 256, 0, stream>>>(x, gw, nw, w1, w2, xn, w1b, w2b,
                                                  topk_id, topk_w, probbuf);
  k_stats<<<1, 256, 0, stream>>>(topk_id, topk_w, probbuf, counts, bases, tilebase,
                                 slots_of, tok_of, slot_w, out + (size_t)T_TOK * DD);
  k_gemm<1024, 2048, 0><<<GEMM_GRID, 256, 0, stream>>>(xn, w1b, counts, bases, tilebase, tok_of, Hg);
  k_gemm<2048, 1024, 1><<<GEMM_GRID, 256, 0, stream>>>(Hg, w2b, counts, bases, tilebase, nullptr, Og);
  k_combine<<<T_TOK * DD / 8 / 256, 256, 0, stream>>>(x, Og, slots_of, slot_w, scale, out);
}